// Round 6
// baseline (664.896 us; speedup 1.0000x reference)
//
#include <hip/hip_runtime.h>
#include <math.h>

#define BATCH 256
#define T 1024
#define IN 19
#define H 128

// tanh via v_exp_f32: tanh(x)=sign(x)*(1-2/(exp(2|x|)+1)); exact to ~1e-7.
__device__ __forceinline__ float fast_tanh(float x) {
    float ax = fabsf(x);
    float e  = __expf(2.0f * ax);
    float r  = 1.0f - 2.0f / (e + 1.0f);
    return copysignf(r, x);
}

// DPP cross-lane move (VALU-only, no LDS pipe).
template <int CTRL>
__device__ __forceinline__ float dppf(float v) {
    return __int_as_float(__builtin_amdgcn_update_dpp(
        0, __float_as_int(v), CTRL, 0xF, 0xF, true));
}
#define XOR1 0xB1   // quad_perm [1,0,3,2]  : lane ^= 1
#define XOR2 0x4E   // quad_perm [2,3,0,1]  : lane ^= 2
#define XOR8 0x128  // row_ror:8            : lane ^= 8 (within 16-lane row)

// Lightweight barrier: waits LDS only (NO vmcnt drain — global loads/stores
// stay in flight across steps). asm memory-clobber pair fences compiler
// code motion on both sides of s_barrier. Side effect used by the P
// pipeline: lgkmcnt(0) retires last interval's ds_reads, so registers
// loaded in interval j-1 are valid VALU inputs at interval j.
__device__ __forceinline__ void sync_fast() {
    asm volatile("s_waitcnt lgkmcnt(0)" ::: "memory");
    __builtin_amdgcn_s_barrier();
    asm volatile("" ::: "memory");
}

// Padded LDS offset for hidden unit u: 16-float slices at stride 20.
__device__ __forceinline__ int uoff(int u) { return (u >> 4) * 20 + (u & 15); }

// ---------------------------------------------------------------------------
// Single fused kernel. 256 blocks x 512 threads (8 waves, 2/SIMD, 1 block/CU).
// Interval j (one barrier period), pipeline roles:
//   S0 (tid   0..127): h0_j = tanh(proj0_j + Whh0.h0_{j-1})          [serial]
//   P  (tid 128..383): ISSUE load h0_{j-1}; COMPUTE B_{j-2} from the
//                      registers loaded at interval j-1 (pure VALU at
//                      interval start — fills S0/S1's LDS-wait window).
//                      Waves 4-5 also: proj0_{j+1} (same-interval xbuf read).
//   S1 (tid 384..511): h1_{j-3} = tanh(B_{j-3} + Whh1.h1_{j-4})      [serial]
// vs R5: P is software-pipelined 1 interval deep (R5 showed phase
// alternation: all waves do LDS-phase then VALU-phase in lockstep; P's
// register-resident B-dot now overlaps the serial waves' LDS latency).
// S1 shifted by 1 interval accordingly (t = j-3). All groups execute
// exactly 1028 barriers (1 init + intervals 0..1026).
// Ring audit: h0_j w@j r@{S0:j+1, P-load:j+1} ow@j+4 | B_{j-2} w@j
// r@{S1:j+1} ow@j+4 | proj_{j+1} w@j r@{S0:j+1} | h1_{j-3} w@j r@j+1.
// Garbage writes B_{-2}(slot2,@j0) / B_{-1}(slot3,@j1) are dead: S1's
// first reads are B_0@j3(slot0), B_1@j4(slot1), B_2@j5(slot2,w@j4). ✓
// ---------------------------------------------------------------------------
__global__ __launch_bounds__(512, 2)
void fused_rnn(const float* __restrict__ x,      // [B,T,IN]
               const float* __restrict__ Wih0,   // [H,IN]
               const float* __restrict__ Whh0,   // [H,H]
               const float* __restrict__ bih0,
               const float* __restrict__ bhh0,
               const float* __restrict__ Wih1,   // [H,H]
               const float* __restrict__ Whh1,   // [H,H]
               const float* __restrict__ bih1,
               const float* __restrict__ bhh1,
               float* __restrict__ out) {        // [B,T,H]
    const int b   = blockIdx.x;
    const int tid = threadIdx.x;

    __shared__ __align__(16) float h0ring[4][160];
    __shared__ __align__(16) float h1ring[4][160];
    __shared__ __align__(16) float Bring[4][H];
    __shared__ __align__(16) float projring[4][H];   // proj0 for step k at [k&3]
    // x chunks: 8 steps x 19 floats, stride 20. Chunk c holds rows 8c+1..8c+8.
    __shared__ __align__(16) float xbuf[2][8 * 20];

    if (tid < 128) {
        // =================== S0 (pure recurrence, irreducibly serial) =======
        __builtin_amdgcn_s_setprio(1);
        const bool b0 = tid & 1, b1 = tid & 2, b2 = tid & 8;
        const int s    = (tid & 3) | ((tid & 8) >> 1);          // slice 0..7
        const int G    = (tid >> 4) * 2 + ((tid >> 2) & 1);     // group 0..15
        const int ub   = G * 8;
        const int ufin = ub + (b0 ? 4 : 0) + (b1 ? 2 : 0) + (b2 ? 1 : 0);

        float wA[8][16];
#pragma unroll
        for (int u = 0; u < 8; ++u) {
            const float* wr = Whh0 + (size_t)(ub + u) * H + s * 16;
#pragma unroll
            for (int c = 0; c < 16; c += 4) {
                float4 v = *(const float4*)&wr[c];
                wA[u][c] = v.x; wA[u][c+1] = v.y; wA[u][c+2] = v.z; wA[u][c+3] = v.w;
            }
        }
        // prologue: proj_0 self-computed (P's ring starts at proj_1)
        {
            const float* wr = Wih0 + ufin * IN;
            const float* xr = x + (size_t)b * T * IN;   // row 0
            float acc = bih0[ufin] + bhh0[ufin];
#pragma unroll
            for (int f = 0; f < IN; ++f) acc = fmaf(xr[f], wr[f], acc);
            projring[0][ufin] = acc;
        }
        h0ring[3][uoff(ufin)] = 0.0f;   // h0_{-1}
        sync_fast();                     // init barrier

        const int so = s * 20;
        const int wo = uoff(ufin);
        for (int ko = 0; ko < T; ko += 8) {
#pragma unroll
            for (int j = 0; j < 8; ++j) {
                const float* hp = &h0ring[(j + 3) & 3][so];
                float pcur = projring[j & 3][ufin];
                float d0=0,d1=0,d2=0,d3=0,d4=0,d5=0,d6=0,d7=0;
#pragma unroll
                for (int c = 0; c < 16; c += 4) {
                    float4 hv = *(const float4*)&hp[c];
                    d0 = fmaf(wA[0][c],hv.x,d0); d0 = fmaf(wA[0][c+1],hv.y,d0); d0 = fmaf(wA[0][c+2],hv.z,d0); d0 = fmaf(wA[0][c+3],hv.w,d0);
                    d1 = fmaf(wA[1][c],hv.x,d1); d1 = fmaf(wA[1][c+1],hv.y,d1); d1 = fmaf(wA[1][c+2],hv.z,d1); d1 = fmaf(wA[1][c+3],hv.w,d1);
                    d2 = fmaf(wA[2][c],hv.x,d2); d2 = fmaf(wA[2][c+1],hv.y,d2); d2 = fmaf(wA[2][c+2],hv.z,d2); d2 = fmaf(wA[2][c+3],hv.w,d2);
                    d3 = fmaf(wA[3][c],hv.x,d3); d3 = fmaf(wA[3][c+1],hv.y,d3); d3 = fmaf(wA[3][c+2],hv.z,d3); d3 = fmaf(wA[3][c+3],hv.w,d3);
                    d4 = fmaf(wA[4][c],hv.x,d4); d4 = fmaf(wA[4][c+1],hv.y,d4); d4 = fmaf(wA[4][c+2],hv.z,d4); d4 = fmaf(wA[4][c+3],hv.w,d4);
                    d5 = fmaf(wA[5][c],hv.x,d5); d5 = fmaf(wA[5][c+1],hv.y,d5); d5 = fmaf(wA[5][c+2],hv.z,d5); d5 = fmaf(wA[5][c+3],hv.w,d5);
                    d6 = fmaf(wA[6][c],hv.x,d6); d6 = fmaf(wA[6][c+1],hv.y,d6); d6 = fmaf(wA[6][c+2],hv.z,d6); d6 = fmaf(wA[6][c+3],hv.w,d6);
                    d7 = fmaf(wA[7][c],hv.x,d7); d7 = fmaf(wA[7][c+1],hv.y,d7); d7 = fmaf(wA[7][c+2],hv.z,d7); d7 = fmaf(wA[7][c+3],hv.w,d7);
                }
                float e0 = (b0 ? d4 : d0) + dppf<XOR1>(b0 ? d0 : d4);
                float e1 = (b0 ? d5 : d1) + dppf<XOR1>(b0 ? d1 : d5);
                float e2 = (b0 ? d6 : d2) + dppf<XOR1>(b0 ? d2 : d6);
                float e3 = (b0 ? d7 : d3) + dppf<XOR1>(b0 ? d3 : d7);
                float g0 = (b1 ? e2 : e0) + dppf<XOR2>(b1 ? e0 : e2);
                float g1 = (b1 ? e3 : e1) + dppf<XOR2>(b1 ? e1 : e3);
                float f  = (b2 ? g1 : g0) + dppf<XOR8>(b2 ? g0 : g1);
                h0ring[j & 3][wo] = fast_tanh(pcur + f);
                sync_fast();
            }
        }
        sync_fast();   // interval 1024
        sync_fast();   // interval 1025
        sync_fast();   // interval 1026
    } else if (tid < 384) {
        // ============ P (pipelined B-projection + layer-0 input proj) =======
        const int p  = tid - 128;
        const bool b0 = p & 1, b1 = p & 2;
        const int s    = (p & 3) | ((p & 8) >> 1);            // slice 0..7
        const int Gp   = (p >> 4) * 2 + ((p >> 2) & 1);       // group 0..31
        const int ub   = Gp * 4;
        const int ufin = ub + (b0 ? 2 : 0) + (b1 ? 1 : 0);

        float wP[4][16];
#pragma unroll
        for (int u = 0; u < 4; ++u) {
            const float* wr = Wih1 + (size_t)(ub + u) * H + s * 16;
#pragma unroll
            for (int c = 0; c < 16; c += 4) {
                float4 v = *(const float4*)&wr[c];
                wP[u][c] = v.x; wP[u][c+1] = v.y; wP[u][c+2] = v.z; wP[u][c+3] = v.w;
            }
        }
        const float biasP = bih1[ufin] + bhh1[ufin];

        // ---- proj duty: waves 4-5 (p>=128), unit = p-128 ----
        const bool hasProj = (p >= 128);
        const int pu = p - 128;                        // proj unit 0..127
        float wIP[20];
        float biasPr = 0.0f;
        const float* xsrc = x + (size_t)b * T * IN + IN;   // row 1 base
        const int idx0  = pu;
        const int idx1  = pu + 128;
        const bool v1   = hasProj && (pu < 24);
        const int slot0 = hasProj ? ((idx0 / IN) * 20 + idx0 % IN) : 0;
        const int slot1 = hasProj ? ((idx1 / IN) * 20 + idx1 % IN) : 0;
        const int XMAX  = (T - 1) * IN - 1;                // last elem rel to xsrc
        float xr0 = 0.0f, xr1 = 0.0f;

        if (hasProj) {
            const float* wr = Wih0 + (size_t)pu * IN;
#pragma unroll
            for (int f = 0; f < IN; ++f) wIP[f] = wr[f];
            wIP[19] = 0.0f;
            biasPr = bih0[pu] + bhh0[pu];
            if (pu < 8) { xbuf[0][pu * 20 + 19] = 0.0f; xbuf[1][pu * 20 + 19] = 0.0f; }
            xbuf[0][slot0] = xsrc[idx0];
            if (v1) xbuf[0][slot1] = xsrc[idx1];
            xr0 = xsrc[152 + idx0];
            if (v1) xr1 = xsrc[152 + idx1];
        }

        // pipeline registers: hA/hB double-buffer of the h0 slice.
        float4 z4 = {0.0f, 0.0f, 0.0f, 0.0f};
        float4 hA0 = z4, hA1 = z4, hA2 = z4, hA3 = z4;
        float4 hB0 = z4, hB1 = z4, hB2 = z4, hB3 = z4;

        sync_fast();   // init barrier

// B-dot + reduce + conditional Bring write from float4 regs c0..c3.
#define P_BCOMP(c0, c1, c2v, c3v, BSLOT)                                              \
        {                                                                             \
            float d0=0,d1=0,d2=0,d3=0;                                                \
            d0 = fmaf(wP[0][0],  c0.x, d0); d0 = fmaf(wP[0][1],  c0.y, d0);           \
            d0 = fmaf(wP[0][2],  c0.z, d0); d0 = fmaf(wP[0][3],  c0.w, d0);           \
            d1 = fmaf(wP[1][0],  c0.x, d1); d1 = fmaf(wP[1][1],  c0.y, d1);           \
            d1 = fmaf(wP[1][2],  c0.z, d1); d1 = fmaf(wP[1][3],  c0.w, d1);           \
            d2 = fmaf(wP[2][0],  c0.x, d2); d2 = fmaf(wP[2][1],  c0.y, d2);           \
            d2 = fmaf(wP[2][2],  c0.z, d2); d2 = fmaf(wP[2][3],  c0.w, d2);           \
            d3 = fmaf(wP[3][0],  c0.x, d3); d3 = fmaf(wP[3][1],  c0.y, d3);           \
            d3 = fmaf(wP[3][2],  c0.z, d3); d3 = fmaf(wP[3][3],  c0.w, d3);           \
            d0 = fmaf(wP[0][4],  c1.x, d0); d0 = fmaf(wP[0][5],  c1.y, d0);           \
            d0 = fmaf(wP[0][6],  c1.z, d0); d0 = fmaf(wP[0][7],  c1.w, d0);           \
            d1 = fmaf(wP[1][4],  c1.x, d1); d1 = fmaf(wP[1][5],  c1.y, d1);           \
            d1 = fmaf(wP[1][6],  c1.z, d1); d1 = fmaf(wP[1][7],  c1.w, d1);           \
            d2 = fmaf(wP[2][4],  c1.x, d2); d2 = fmaf(wP[2][5],  c1.y, d2);           \
            d2 = fmaf(wP[2][6],  c1.z, d2); d2 = fmaf(wP[2][7],  c1.w, d2);           \
            d3 = fmaf(wP[3][4],  c1.x, d3); d3 = fmaf(wP[3][5],  c1.y, d3);           \
            d3 = fmaf(wP[3][6],  c1.z, d3); d3 = fmaf(wP[3][7],  c1.w, d3);           \
            d0 = fmaf(wP[0][8],  c2v.x, d0); d0 = fmaf(wP[0][9],  c2v.y, d0);         \
            d0 = fmaf(wP[0][10], c2v.z, d0); d0 = fmaf(wP[0][11], c2v.w, d0);         \
            d1 = fmaf(wP[1][8],  c2v.x, d1); d1 = fmaf(wP[1][9],  c2v.y, d1);         \
            d1 = fmaf(wP[1][10], c2v.z, d1); d1 = fmaf(wP[1][11], c2v.w, d1);         \
            d2 = fmaf(wP[2][8],  c2v.x, d2); d2 = fmaf(wP[2][9],  c2v.y, d2);         \
            d2 = fmaf(wP[2][10], c2v.z, d2); d2 = fmaf(wP[2][11], c2v.w, d2);         \
            d3 = fmaf(wP[3][8],  c2v.x, d3); d3 = fmaf(wP[3][9],  c2v.y, d3);         \
            d3 = fmaf(wP[3][10], c2v.z, d3); d3 = fmaf(wP[3][11], c2v.w, d3);         \
            d0 = fmaf(wP[0][12], c3v.x, d0); d0 = fmaf(wP[0][13], c3v.y, d0);         \
            d0 = fmaf(wP[0][14], c3v.z, d0); d0 = fmaf(wP[0][15], c3v.w, d0);         \
            d1 = fmaf(wP[1][12], c3v.x, d1); d1 = fmaf(wP[1][13], c3v.y, d1);         \
            d1 = fmaf(wP[1][14], c3v.z, d1); d1 = fmaf(wP[1][15], c3v.w, d1);         \
            d2 = fmaf(wP[2][12], c3v.x, d2); d2 = fmaf(wP[2][13], c3v.y, d2);         \
            d2 = fmaf(wP[2][14], c3v.z, d2); d2 = fmaf(wP[2][15], c3v.w, d2);         \
            d3 = fmaf(wP[3][12], c3v.x, d3); d3 = fmaf(wP[3][13], c3v.y, d3);         \
            d3 = fmaf(wP[3][14], c3v.z, d3); d3 = fmaf(wP[3][15], c3v.w, d3);         \
            float e0 = (b0 ? d2 : d0) + dppf<XOR1>(b0 ? d0 : d2);                     \
            float e1 = (b0 ? d3 : d1) + dppf<XOR1>(b0 ? d1 : d3);                     \
            float g  = (b1 ? e1 : e0) + dppf<XOR2>(b1 ? e0 : e1);                     \
            g += dppf<XOR8>(g);                                                       \
            if (!(p & 8)) Bring[BSLOT][ufin] = g + biasP;                             \
        }

        const int so = s * 20;
        for (int ko = 0; ko < T; ko += 8) {
            const int cb = (ko >> 3) & 1;
#pragma unroll
            for (int jj = 0; jj < 8; ++jj) {
                // ---- ISSUE: load h0_{j-1} into next buffer (slot (jj+3)&3).
                // Retired by sync_fast's lgkmcnt(0); consumed NEXT interval.
                const float* hp = &h0ring[(jj + 3) & 3][so];
                if ((jj & 1) == 0) {
                    hA0 = *(const float4*)&hp[0];  hA1 = *(const float4*)&hp[4];
                    hA2 = *(const float4*)&hp[8];  hA3 = *(const float4*)&hp[12];
                } else {
                    hB0 = *(const float4*)&hp[0];  hB1 = *(const float4*)&hp[4];
                    hB2 = *(const float4*)&hp[8];  hB3 = *(const float4*)&hp[12];
                }
                // ---- COMPUTE: B_{j-2} from last interval's regs (pure VALU,
                // issues immediately post-barrier). Write slot (jj+2)&3.
                if ((jj & 1) == 0) {
                    P_BCOMP(hB0, hB1, hB2, hB3, ((jj + 2) & 3))
                } else {
                    P_BCOMP(hA0, hA1, hA2, hA3, ((jj + 2) & 3))
                }
                // ---- proj0_{j+1} from x row jj of current chunk ----
                if (hasProj) {
                    const float* xp = &xbuf[cb][jj * 20];
                    float4 xv0 = *(const float4*)&xp[0];
                    float4 xv1 = *(const float4*)&xp[4];
                    float4 xv2 = *(const float4*)&xp[8];
                    float4 xv3 = *(const float4*)&xp[12];
                    float4 xv4 = *(const float4*)&xp[16];   // .w = pad
                    float p0 = biasPr, p1 = 0.0f;
                    p0 = fmaf(xv0.x, wIP[0],  p0); p1 = fmaf(xv0.y, wIP[1],  p1);
                    p0 = fmaf(xv0.z, wIP[2],  p0); p1 = fmaf(xv0.w, wIP[3],  p1);
                    p0 = fmaf(xv1.x, wIP[4],  p0); p1 = fmaf(xv1.y, wIP[5],  p1);
                    p0 = fmaf(xv1.z, wIP[6],  p0); p1 = fmaf(xv1.w, wIP[7],  p1);
                    p0 = fmaf(xv2.x, wIP[8],  p0); p1 = fmaf(xv2.y, wIP[9],  p1);
                    p0 = fmaf(xv2.z, wIP[10], p0); p1 = fmaf(xv2.w, wIP[11], p1);
                    p0 = fmaf(xv3.x, wIP[12], p0); p1 = fmaf(xv3.y, wIP[13], p1);
                    p0 = fmaf(xv3.z, wIP[14], p0); p1 = fmaf(xv3.w, wIP[15], p1);
                    p0 = fmaf(xv4.x, wIP[16], p0); p1 = fmaf(xv4.y, wIP[17], p1);
                    p0 = fmaf(xv4.z, wIP[18], p0); p1 = fmaf(xv4.w, wIP[19], p1);
                    projring[(jj + 1) & 3][pu] = p0 + p1;
                    if (jj == 7) {
                        // publish chunk c+1 (pre-barrier), fetch chunk c+2
                        float* xd = xbuf[cb ^ 1];
                        xd[slot0] = xr0;
                        if (v1) xd[slot1] = xr1;
                        const int c2 = (ko >> 3) + 2;
                        int o0 = 152 * c2 + idx0; o0 = o0 > XMAX ? XMAX : o0;
                        int o1 = 152 * c2 + idx1; o1 = o1 > XMAX ? XMAX : o1;
                        xr0 = xsrc[o0];
                        if (v1) xr1 = xsrc[o1];
                    }
                }
                sync_fast();
            }
        }
        // ---- epilogue ----
        // interval 1024 (even): LOAD h0_1023 (slot 3) -> hA; COMPUTE B_1022
        // from hB (loaded at interval 1023) -> slot 2.
        {
            const float* hp = &h0ring[3][so];
            hA0 = *(const float4*)&hp[0];  hA1 = *(const float4*)&hp[4];
            hA2 = *(const float4*)&hp[8];  hA3 = *(const float4*)&hp[12];
            P_BCOMP(hB0, hB1, hB2, hB3, 2)
        }
        sync_fast();   // interval 1024
        // interval 1025: COMPUTE B_1023 from hA -> slot 3.
        P_BCOMP(hA0, hA1, hA2, hA3, 3)
        sync_fast();   // interval 1025
        sync_fast();   // interval 1026
#undef P_BCOMP
    } else {
        // =================== S1 (h1_{j-3} at interval j) ===================
        __builtin_amdgcn_s_setprio(1);
        const int w  = tid - 384;
        const bool b0 = w & 1, b1 = w & 2, b2 = w & 8;
        const int s    = (w & 3) | ((w & 8) >> 1);
        const int G    = (w >> 4) * 2 + ((w >> 2) & 1);
        const int ub   = G * 8;
        const int ufin = ub + (b0 ? 4 : 0) + (b1 ? 2 : 0) + (b2 ? 1 : 0);

        float wA[8][16];
#pragma unroll
        for (int u = 0; u < 8; ++u) {
            const float* wr = Whh1 + (size_t)(ub + u) * H + s * 16;
#pragma unroll
            for (int c = 0; c < 16; c += 4) {
                float4 v = *(const float4*)&wr[c];
                wA[u][c] = v.x; wA[u][c+1] = v.y; wA[u][c+2] = v.z; wA[u][c+3] = v.w;
            }
        }
        float* orow = out + (size_t)b * T * H + ufin;
        float sbuf[8];

        h1ring[3][uoff(ufin)] = 0.0f;   // h1_{-1}
        sync_fast();   // init barrier
        sync_fast();   // interval 0
        sync_fast();   // interval 1
        sync_fast();   // interval 2

        const int so = s * 20;
        const int wo = uoff(ufin);
        for (int ko = 3; ko < 1027; ko += 8) {
#pragma unroll
            for (int j = 0; j < 8; ++j) {
                // interval ko+j: t = ko+j-3. h1_{t-1} slot (j+3)&3;
                // B_t slot j&3 (written by P at interval t+2 = ko+j-1).
                const float* hp = &h1ring[(j + 3) & 3][so];
                float Bg = Bring[j & 3][ufin];
                float d0=0,d1=0,d2=0,d3=0,d4=0,d5=0,d6=0,d7=0;
#pragma unroll
                for (int c = 0; c < 16; c += 4) {
                    float4 hv = *(const float4*)&hp[c];
                    d0 = fmaf(wA[0][c],hv.x,d0); d0 = fmaf(wA[0][c+1],hv.y,d0); d0 = fmaf(wA[0][c+2],hv.z,d0); d0 = fmaf(wA[0][c+3],hv.w,d0);
                    d1 = fmaf(wA[1][c],hv.x,d1); d1 = fmaf(wA[1][c+1],hv.y,d1); d1 = fmaf(wA[1][c+2],hv.z,d1); d1 = fmaf(wA[1][c+3],hv.w,d1);
                    d2 = fmaf(wA[2][c],hv.x,d2); d2 = fmaf(wA[2][c+1],hv.y,d2); d2 = fmaf(wA[2][c+2],hv.z,d2); d2 = fmaf(wA[2][c+3],hv.w,d2);
                    d3 = fmaf(wA[3][c],hv.x,d3); d3 = fmaf(wA[3][c+1],hv.y,d3); d3 = fmaf(wA[3][c+2],hv.z,d3); d3 = fmaf(wA[3][c+3],hv.w,d3);
                    d4 = fmaf(wA[4][c],hv.x,d4); d4 = fmaf(wA[4][c+1],hv.y,d4); d4 = fmaf(wA[4][c+2],hv.z,d4); d4 = fmaf(wA[4][c+3],hv.w,d4);
                    d5 = fmaf(wA[5][c],hv.x,d5); d5 = fmaf(wA[5][c+1],hv.y,d5); d5 = fmaf(wA[5][c+2],hv.z,d5); d5 = fmaf(wA[5][c+3],hv.w,d5);
                    d6 = fmaf(wA[6][c],hv.x,d6); d6 = fmaf(wA[6][c+1],hv.y,d6); d6 = fmaf(wA[6][c+2],hv.z,d6); d6 = fmaf(wA[6][c+3],hv.w,d6);
                    d7 = fmaf(wA[7][c],hv.x,d7); d7 = fmaf(wA[7][c+1],hv.y,d7); d7 = fmaf(wA[7][c+2],hv.z,d7); d7 = fmaf(wA[7][c+3],hv.w,d7);
                }
                float e0 = (b0 ? d4 : d0) + dppf<XOR1>(b0 ? d0 : d4);
                float e1 = (b0 ? d5 : d1) + dppf<XOR1>(b0 ? d1 : d5);
                float e2 = (b0 ? d6 : d2) + dppf<XOR1>(b0 ? d2 : d6);
                float e3 = (b0 ? d7 : d3) + dppf<XOR1>(b0 ? d3 : d7);
                float g0 = (b1 ? e2 : e0) + dppf<XOR2>(b1 ? e0 : e2);
                float g1 = (b1 ? e3 : e1) + dppf<XOR2>(b1 ? e1 : e3);
                float f  = (b2 ? g1 : g0) + dppf<XOR8>(b2 ? g0 : g1);
                float h1v = fast_tanh(Bg + f);
                h1ring[j & 3][wo] = h1v;
                sbuf[j] = h1v;
                if (j == 7) {                  // burst-write t = ko-3 .. ko+4
                    const int t0 = ko - 3;
#pragma unroll
                    for (int i = 0; i < 8; ++i)
                        orow[(size_t)(t0 + i) * H] = sbuf[i];
                }
                sync_fast();
            }
        }
        // no trailing barriers needed for S1 (last interval is 1026)
    }
}

// ---------------------------------------------------------------------------
extern "C" void kernel_launch(void* const* d_in, const int* in_sizes, int n_in,
                              void* d_out, int out_size, void* d_ws, size_t ws_size,
                              hipStream_t stream) {
    const float* x     = (const float*)d_in[0];
    const float* W_ih0 = (const float*)d_in[1];
    const float* W_hh0 = (const float*)d_in[2];
    const float* b_ih0 = (const float*)d_in[3];
    const float* b_hh0 = (const float*)d_in[4];
    const float* W_ih1 = (const float*)d_in[5];
    const float* W_hh1 = (const float*)d_in[6];
    const float* b_ih1 = (const float*)d_in[7];
    const float* b_hh1 = (const float*)d_in[8];

    float* out = (float*)d_out;

    fused_rnn<<<BATCH, 512, 0, stream>>>(x, W_ih0, W_hh0, b_ih0, b_hh0,
                                         W_ih1, W_hh1, b_ih1, b_hh1, out);
}

// Round 7
// 607.987 us; speedup vs baseline: 1.0936x; 1.0936x over previous
//
#include <hip/hip_runtime.h>
#include <math.h>

#define BATCH 256
#define T 1024
#define IN 19
#define H 128

// tanh via v_exp_f32: tanh(x)=sign(x)*(1-2/(exp(2|x|)+1)); exact to ~1e-7.
__device__ __forceinline__ float fast_tanh(float x) {
    float ax = fabsf(x);
    float e  = __expf(2.0f * ax);
    float r  = 1.0f - 2.0f / (e + 1.0f);
    return copysignf(r, x);
}

// DPP cross-lane move (VALU-only, no LDS pipe).
template <int CTRL>
__device__ __forceinline__ float dppf(float v) {
    return __int_as_float(__builtin_amdgcn_update_dpp(
        0, __float_as_int(v), CTRL, 0xF, 0xF, true));
}
#define XOR1 0xB1   // quad_perm [1,0,3,2]  : lane ^= 1
#define XOR2 0x4E   // quad_perm [2,3,0,1]  : lane ^= 2
#define XOR8 0x128  // row_ror:8            : lane ^= 8 (within 16-lane row)

// Lightweight barrier: waits LDS only (NO vmcnt drain — global loads/stores
// stay in flight across steps). asm memory-clobber pair fences compiler
// code motion on both sides of s_barrier.
__device__ __forceinline__ void sync_fast() {
    asm volatile("s_waitcnt lgkmcnt(0)" ::: "memory");
    __builtin_amdgcn_s_barrier();
    asm volatile("" ::: "memory");
}

// Padded LDS offset for hidden unit u: 16-float slices at stride 20.
__device__ __forceinline__ int uoff(int u) { return (u >> 4) * 20 + (u & 15); }

// ---------------------------------------------------------------------------
// Single fused kernel. 256 blocks x 512 threads (8 waves, 2/SIMD, 1 block/CU).
//   S0 (tid   0..127, 2 waves): h0_k = tanh(proj0_k + Whh0.h0_{k-1})
//   P  (tid 128..383, 4 waves): B_{k-1} = Wih1.h0_{k-1} + b1
//                               waves 4-5 (p>=128) also: proj0_{k+1}
//   S1 (tid 384..511, 2 waves): h1_{k-2} = tanh(B_{k-2} + Whh1.h1_{k-3})
// Structure identical to R5 (546us baseline; R6's P-pipelining regressed and
// is reverted). ONE change: amdgpu_waves_per_eu(2,2). R0-R6 all compiled to
// VGPR_Count=84 — too small for the 128 weight floats each S0/S1 thread
// needs resident, so the compiler rematerialized weight loads from global
// memory inside the 1024-step loop (the dominant, unmodeled per-step cost;
// occupancy heuristic targeted ~6 waves/EU while the launch runs 2). Pinning
// waves/EU to exactly 2 gives the allocator the full 256-VGPR budget so
// wA/wP/wIP stay register-resident across the loop.
// All groups execute exactly 1027 barriers.
// ---------------------------------------------------------------------------
__global__ __launch_bounds__(512)
__attribute__((amdgpu_waves_per_eu(2, 2)))
void fused_rnn(const float* __restrict__ x,      // [B,T,IN]
               const float* __restrict__ Wih0,   // [H,IN]
               const float* __restrict__ Whh0,   // [H,H]
               const float* __restrict__ bih0,
               const float* __restrict__ bhh0,
               const float* __restrict__ Wih1,   // [H,H]
               const float* __restrict__ Whh1,   // [H,H]
               const float* __restrict__ bih1,
               const float* __restrict__ bhh1,
               float* __restrict__ out) {        // [B,T,H]
    const int b   = blockIdx.x;
    const int tid = threadIdx.x;

    __shared__ __align__(16) float h0ring[4][160];
    __shared__ __align__(16) float h1ring[4][160];
    __shared__ __align__(16) float Bring[4][H];
    __shared__ __align__(16) float projring[4][H];   // proj0 for step k at [k&3]
    // x chunks: 8 steps x 19 floats, stride 20. Chunk c holds rows 8c+1..8c+8.
    __shared__ __align__(16) float xbuf[2][8 * 20];

    if (tid < 128) {
        // =================== S0 (pure recurrence) ===================
        __builtin_amdgcn_s_setprio(1);
        const bool b0 = tid & 1, b1 = tid & 2, b2 = tid & 8;
        const int s    = (tid & 3) | ((tid & 8) >> 1);          // slice 0..7
        const int G    = (tid >> 4) * 2 + ((tid >> 2) & 1);     // group 0..15
        const int ub   = G * 8;
        const int ufin = ub + (b0 ? 4 : 0) + (b1 ? 2 : 0) + (b2 ? 1 : 0);

        float wA[8][16];
#pragma unroll
        for (int u = 0; u < 8; ++u) {
            const float* wr = Whh0 + (size_t)(ub + u) * H + s * 16;
#pragma unroll
            for (int c = 0; c < 16; c += 4) {
                float4 v = *(const float4*)&wr[c];
                wA[u][c] = v.x; wA[u][c+1] = v.y; wA[u][c+2] = v.z; wA[u][c+3] = v.w;
            }
        }
        // prologue: proj_0 self-computed (P's ring starts at proj_1)
        {
            const float* wr = Wih0 + ufin * IN;
            const float* xr = x + (size_t)b * T * IN;   // row 0
            float acc = bih0[ufin] + bhh0[ufin];
#pragma unroll
            for (int f = 0; f < IN; ++f) acc = fmaf(xr[f], wr[f], acc);
            projring[0][ufin] = acc;
        }
        h0ring[3][uoff(ufin)] = 0.0f;   // h0_{-1}
        sync_fast();                     // init barrier

        const int so = s * 20;
        const int wo = uoff(ufin);
        for (int ko = 0; ko < T; ko += 8) {
#pragma unroll
            for (int j = 0; j < 8; ++j) {
                const float* hp = &h0ring[(j + 3) & 3][so];
                float pcur = projring[j & 3][ufin];
                float d0=0,d1=0,d2=0,d3=0,d4=0,d5=0,d6=0,d7=0;
#pragma unroll
                for (int c = 0; c < 16; c += 4) {
                    float4 hv = *(const float4*)&hp[c];
                    d0 = fmaf(wA[0][c],hv.x,d0); d0 = fmaf(wA[0][c+1],hv.y,d0); d0 = fmaf(wA[0][c+2],hv.z,d0); d0 = fmaf(wA[0][c+3],hv.w,d0);
                    d1 = fmaf(wA[1][c],hv.x,d1); d1 = fmaf(wA[1][c+1],hv.y,d1); d1 = fmaf(wA[1][c+2],hv.z,d1); d1 = fmaf(wA[1][c+3],hv.w,d1);
                    d2 = fmaf(wA[2][c],hv.x,d2); d2 = fmaf(wA[2][c+1],hv.y,d2); d2 = fmaf(wA[2][c+2],hv.z,d2); d2 = fmaf(wA[2][c+3],hv.w,d2);
                    d3 = fmaf(wA[3][c],hv.x,d3); d3 = fmaf(wA[3][c+1],hv.y,d3); d3 = fmaf(wA[3][c+2],hv.z,d3); d3 = fmaf(wA[3][c+3],hv.w,d3);
                    d4 = fmaf(wA[4][c],hv.x,d4); d4 = fmaf(wA[4][c+1],hv.y,d4); d4 = fmaf(wA[4][c+2],hv.z,d4); d4 = fmaf(wA[4][c+3],hv.w,d4);
                    d5 = fmaf(wA[5][c],hv.x,d5); d5 = fmaf(wA[5][c+1],hv.y,d5); d5 = fmaf(wA[5][c+2],hv.z,d5); d5 = fmaf(wA[5][c+3],hv.w,d5);
                    d6 = fmaf(wA[6][c],hv.x,d6); d6 = fmaf(wA[6][c+1],hv.y,d6); d6 = fmaf(wA[6][c+2],hv.z,d6); d6 = fmaf(wA[6][c+3],hv.w,d6);
                    d7 = fmaf(wA[7][c],hv.x,d7); d7 = fmaf(wA[7][c+1],hv.y,d7); d7 = fmaf(wA[7][c+2],hv.z,d7); d7 = fmaf(wA[7][c+3],hv.w,d7);
                }
                float e0 = (b0 ? d4 : d0) + dppf<XOR1>(b0 ? d0 : d4);
                float e1 = (b0 ? d5 : d1) + dppf<XOR1>(b0 ? d1 : d5);
                float e2 = (b0 ? d6 : d2) + dppf<XOR1>(b0 ? d2 : d6);
                float e3 = (b0 ? d7 : d3) + dppf<XOR1>(b0 ? d3 : d7);
                float g0 = (b1 ? e2 : e0) + dppf<XOR2>(b1 ? e0 : e2);
                float g1 = (b1 ? e3 : e1) + dppf<XOR2>(b1 ? e1 : e3);
                float f  = (b2 ? g1 : g0) + dppf<XOR8>(b2 ? g0 : g1);
                h0ring[j & 3][wo] = fast_tanh(pcur + f);
                sync_fast();
            }
        }
        sync_fast();   // interval 1024
        sync_fast();   // interval 1025
    } else if (tid < 384) {
        // =================== P (B-projection + layer-0 input projection) ====
        const int p  = tid - 128;
        const bool b0 = p & 1, b1 = p & 2;
        const int s    = (p & 3) | ((p & 8) >> 1);            // slice 0..7
        const int Gp   = (p >> 4) * 2 + ((p >> 2) & 1);       // group 0..31
        const int ub   = Gp * 4;
        const int ufin = ub + (b0 ? 2 : 0) + (b1 ? 1 : 0);

        float wP[4][16];
#pragma unroll
        for (int u = 0; u < 4; ++u) {
            const float* wr = Wih1 + (size_t)(ub + u) * H + s * 16;
#pragma unroll
            for (int c = 0; c < 16; c += 4) {
                float4 v = *(const float4*)&wr[c];
                wP[u][c] = v.x; wP[u][c+1] = v.y; wP[u][c+2] = v.z; wP[u][c+3] = v.w;
            }
        }
        const float biasP = bih1[ufin] + bhh1[ufin];

        // ---- proj duty: waves 4-5 (p>=128), unit = p-128 ----
        const bool hasProj = (p >= 128);
        const int pu = p - 128;                        // proj unit 0..127
        float wIP[20];
        float biasPr = 0.0f;
        const float* xsrc = x + (size_t)b * T * IN + IN;   // row 1 base
        const int idx0  = pu;
        const int idx1  = pu + 128;
        const bool v1   = hasProj && (pu < 24);
        const int slot0 = hasProj ? ((idx0 / IN) * 20 + idx0 % IN) : 0;
        const int slot1 = hasProj ? ((idx1 / IN) * 20 + idx1 % IN) : 0;
        const int XMAX  = (T - 1) * IN - 1;                // last elem rel to xsrc
        float xr0 = 0.0f, xr1 = 0.0f;

        if (hasProj) {
            const float* wr = Wih0 + (size_t)pu * IN;
#pragma unroll
            for (int f = 0; f < IN; ++f) wIP[f] = wr[f];
            wIP[19] = 0.0f;
            biasPr = bih0[pu] + bhh0[pu];
            if (pu < 8) { xbuf[0][pu * 20 + 19] = 0.0f; xbuf[1][pu * 20 + 19] = 0.0f; }
            xbuf[0][slot0] = xsrc[idx0];
            if (v1) xbuf[0][slot1] = xsrc[idx1];
            xr0 = xsrc[152 + idx0];
            if (v1) xr1 = xsrc[152 + idx1];
        }
        sync_fast();   // init barrier

        const int so = s * 20;
        for (int ko = 0; ko < T; ko += 8) {
            const int cb = (ko >> 3) & 1;
#pragma unroll
            for (int j = 0; j < 8; ++j) {
                // ---- B_{k-1}: dot over h0_{k-1} (slot (j+3)&3) ----
                const float* hp = &h0ring[(j + 3) & 3][so];
                float d0=0,d1=0,d2=0,d3=0;
#pragma unroll
                for (int c = 0; c < 16; c += 4) {
                    float4 hv = *(const float4*)&hp[c];
                    d0 = fmaf(wP[0][c],hv.x,d0); d0 = fmaf(wP[0][c+1],hv.y,d0); d0 = fmaf(wP[0][c+2],hv.z,d0); d0 = fmaf(wP[0][c+3],hv.w,d0);
                    d1 = fmaf(wP[1][c],hv.x,d1); d1 = fmaf(wP[1][c+1],hv.y,d1); d1 = fmaf(wP[1][c+2],hv.z,d1); d1 = fmaf(wP[1][c+3],hv.w,d1);
                    d2 = fmaf(wP[2][c],hv.x,d2); d2 = fmaf(wP[2][c+1],hv.y,d2); d2 = fmaf(wP[2][c+2],hv.z,d2); d2 = fmaf(wP[2][c+3],hv.w,d2);
                    d3 = fmaf(wP[3][c],hv.x,d3); d3 = fmaf(wP[3][c+1],hv.y,d3); d3 = fmaf(wP[3][c+2],hv.z,d3); d3 = fmaf(wP[3][c+3],hv.w,d3);
                }
                float e0 = (b0 ? d2 : d0) + dppf<XOR1>(b0 ? d0 : d2);
                float e1 = (b0 ? d3 : d1) + dppf<XOR1>(b0 ? d1 : d3);
                float g  = (b1 ? e1 : e0) + dppf<XOR2>(b1 ? e0 : e1);
                g += dppf<XOR8>(g);
                if (!(p & 8)) Bring[(j + 3) & 3][ufin] = g + biasP;
                // ---- proj0_{k+1} from x row j of current chunk ----
                if (hasProj) {
                    const float* xp = &xbuf[cb][j * 20];
                    float4 xv0 = *(const float4*)&xp[0];
                    float4 xv1 = *(const float4*)&xp[4];
                    float4 xv2 = *(const float4*)&xp[8];
                    float4 xv3 = *(const float4*)&xp[12];
                    float4 xv4 = *(const float4*)&xp[16];   // .w = pad
                    float p0 = biasPr, p1 = 0.0f;
                    p0 = fmaf(xv0.x, wIP[0],  p0); p1 = fmaf(xv0.y, wIP[1],  p1);
                    p0 = fmaf(xv0.z, wIP[2],  p0); p1 = fmaf(xv0.w, wIP[3],  p1);
                    p0 = fmaf(xv1.x, wIP[4],  p0); p1 = fmaf(xv1.y, wIP[5],  p1);
                    p0 = fmaf(xv1.z, wIP[6],  p0); p1 = fmaf(xv1.w, wIP[7],  p1);
                    p0 = fmaf(xv2.x, wIP[8],  p0); p1 = fmaf(xv2.y, wIP[9],  p1);
                    p0 = fmaf(xv2.z, wIP[10], p0); p1 = fmaf(xv2.w, wIP[11], p1);
                    p0 = fmaf(xv3.x, wIP[12], p0); p1 = fmaf(xv3.y, wIP[13], p1);
                    p0 = fmaf(xv3.z, wIP[14], p0); p1 = fmaf(xv3.w, wIP[15], p1);
                    p0 = fmaf(xv4.x, wIP[16], p0); p1 = fmaf(xv4.y, wIP[17], p1);
                    p0 = fmaf(xv4.z, wIP[18], p0); p1 = fmaf(xv4.w, wIP[19], p1);
                    projring[(j + 1) & 3][pu] = p0 + p1;
                    if (j == 7) {
                        // publish chunk c+1 (pre-barrier), fetch chunk c+2
                        float* xd = xbuf[cb ^ 1];
                        xd[slot0] = xr0;
                        if (v1) xd[slot1] = xr1;
                        const int c2 = (ko >> 3) + 2;
                        int o0 = 152 * c2 + idx0; o0 = o0 > XMAX ? XMAX : o0;
                        int o1 = 152 * c2 + idx1; o1 = o1 > XMAX ? XMAX : o1;
                        xr0 = xsrc[o0];
                        if (v1) xr1 = xsrc[o1];
                    }
                }
                sync_fast();
            }
        }
        // ---- epilogue (interval 1024): B_1023 from h0_1023 (slot 3) ----
        {
            const float* hp = &h0ring[3][so];
            float d0=0,d1=0,d2=0,d3=0;
#pragma unroll
            for (int c = 0; c < 16; c += 4) {
                float4 hv = *(const float4*)&hp[c];
                d0 = fmaf(wP[0][c],hv.x,d0); d0 = fmaf(wP[0][c+1],hv.y,d0); d0 = fmaf(wP[0][c+2],hv.z,d0); d0 = fmaf(wP[0][c+3],hv.w,d0);
                d1 = fmaf(wP[1][c],hv.x,d1); d1 = fmaf(wP[1][c+1],hv.y,d1); d1 = fmaf(wP[1][c+2],hv.z,d1); d1 = fmaf(wP[1][c+3],hv.w,d1);
                d2 = fmaf(wP[2][c],hv.x,d2); d2 = fmaf(wP[2][c+1],hv.y,d2); d2 = fmaf(wP[2][c+2],hv.z,d2); d2 = fmaf(wP[2][c+3],hv.w,d2);
                d3 = fmaf(wP[3][c],hv.x,d3); d3 = fmaf(wP[3][c+1],hv.y,d3); d3 = fmaf(wP[3][c+2],hv.z,d3); d3 = fmaf(wP[3][c+3],hv.w,d3);
            }
            float e0 = (b0 ? d2 : d0) + dppf<XOR1>(b0 ? d0 : d2);
            float e1 = (b0 ? d3 : d1) + dppf<XOR1>(b0 ? d1 : d3);
            float g  = (b1 ? e1 : e0) + dppf<XOR2>(b1 ? e0 : e1);
            g += dppf<XOR8>(g);
            if (!(p & 8)) Bring[3][ufin] = g + biasP;
        }
        sync_fast();   // interval 1024
        sync_fast();   // interval 1025
    } else {
        // =================== S1 ===================
        __builtin_amdgcn_s_setprio(1);
        const int w  = tid - 384;
        const bool b0 = w & 1, b1 = w & 2, b2 = w & 8;
        const int s    = (w & 3) | ((w & 8) >> 1);
        const int G    = (w >> 4) * 2 + ((w >> 2) & 1);
        const int ub   = G * 8;
        const int ufin = ub + (b0 ? 4 : 0) + (b1 ? 2 : 0) + (b2 ? 1 : 0);

        float wA[8][16];
#pragma unroll
        for (int u = 0; u < 8; ++u) {
            const float* wr = Whh1 + (size_t)(ub + u) * H + s * 16;
#pragma unroll
            for (int c = 0; c < 16; c += 4) {
                float4 v = *(const float4*)&wr[c];
                wA[u][c] = v.x; wA[u][c+1] = v.y; wA[u][c+2] = v.z; wA[u][c+3] = v.w;
            }
        }
        float* orow = out + (size_t)b * T * H + ufin;
        float sbuf[8];

        h1ring[3][uoff(ufin)] = 0.0f;   // h1_{-1}
        sync_fast();   // init barrier
        sync_fast();   // interval 0
        sync_fast();   // interval 1

        const int so = s * 20;
        const int wo = uoff(ufin);
        for (int ko = 2; ko < 1026; ko += 8) {
#pragma unroll
            for (int j = 0; j < 8; ++j) {
                // ko%8==2: h1_{t-1} slot -> (j+3)&3 ; B_{k-2} slot -> j&3
                const float* hp = &h1ring[(j + 3) & 3][so];
                float Bg = Bring[j & 3][ufin];
                float d0=0,d1=0,d2=0,d3=0,d4=0,d5=0,d6=0,d7=0;
#pragma unroll
                for (int c = 0; c < 16; c += 4) {
                    float4 hv = *(const float4*)&hp[c];
                    d0 = fmaf(wA[0][c],hv.x,d0); d0 = fmaf(wA[0][c+1],hv.y,d0); d0 = fmaf(wA[0][c+2],hv.z,d0); d0 = fmaf(wA[0][c+3],hv.w,d0);
                    d1 = fmaf(wA[1][c],hv.x,d1); d1 = fmaf(wA[1][c+1],hv.y,d1); d1 = fmaf(wA[1][c+2],hv.z,d1); d1 = fmaf(wA[1][c+3],hv.w,d1);
                    d2 = fmaf(wA[2][c],hv.x,d2); d2 = fmaf(wA[2][c+1],hv.y,d2); d2 = fmaf(wA[2][c+2],hv.z,d2); d2 = fmaf(wA[2][c+3],hv.w,d2);
                    d3 = fmaf(wA[3][c],hv.x,d3); d3 = fmaf(wA[3][c+1],hv.y,d3); d3 = fmaf(wA[3][c+2],hv.z,d3); d3 = fmaf(wA[3][c+3],hv.w,d3);
                    d4 = fmaf(wA[4][c],hv.x,d4); d4 = fmaf(wA[4][c+1],hv.y,d4); d4 = fmaf(wA[4][c+2],hv.z,d4); d4 = fmaf(wA[4][c+3],hv.w,d4);
                    d5 = fmaf(wA[5][c],hv.x,d5); d5 = fmaf(wA[5][c+1],hv.y,d5); d5 = fmaf(wA[5][c+2],hv.z,d5); d5 = fmaf(wA[5][c+3],hv.w,d5);
                    d6 = fmaf(wA[6][c],hv.x,d6); d6 = fmaf(wA[6][c+1],hv.y,d6); d6 = fmaf(wA[6][c+2],hv.z,d6); d6 = fmaf(wA[6][c+3],hv.w,d6);
                    d7 = fmaf(wA[7][c],hv.x,d7); d7 = fmaf(wA[7][c+1],hv.y,d7); d7 = fmaf(wA[7][c+2],hv.z,d7); d7 = fmaf(wA[7][c+3],hv.w,d7);
                }
                float e0 = (b0 ? d4 : d0) + dppf<XOR1>(b0 ? d0 : d4);
                float e1 = (b0 ? d5 : d1) + dppf<XOR1>(b0 ? d1 : d5);
                float e2 = (b0 ? d6 : d2) + dppf<XOR1>(b0 ? d2 : d6);
                float e3 = (b0 ? d7 : d3) + dppf<XOR1>(b0 ? d3 : d7);
                float g0 = (b1 ? e2 : e0) + dppf<XOR2>(b1 ? e0 : e2);
                float g1 = (b1 ? e3 : e1) + dppf<XOR2>(b1 ? e1 : e3);
                float f  = (b2 ? g1 : g0) + dppf<XOR8>(b2 ? g0 : g1);
                float h1v = fast_tanh(Bg + f);
                h1ring[j & 3][wo] = h1v;
                sbuf[j] = h1v;
                if (j == 7) {                  // burst-write t = ko-2 .. ko+5
                    const int t0 = ko - 2;
#pragma unroll
                    for (int i = 0; i < 8; ++i)
                        orow[(size_t)(t0 + i) * H] = sbuf[i];
                }
                sync_fast();
            }
        }
        // no trailing barriers needed for S1 (last interval is 1025)
    }
}

// ---------------------------------------------------------------------------
extern "C" void kernel_launch(void* const* d_in, const int* in_sizes, int n_in,
                              void* d_out, int out_size, void* d_ws, size_t ws_size,
                              hipStream_t stream) {
    const float* x     = (const float*)d_in[0];
    const float* W_ih0 = (const float*)d_in[1];
    const float* W_hh0 = (const float*)d_in[2];
    const float* b_ih0 = (const float*)d_in[3];
    const float* b_hh0 = (const float*)d_in[4];
    const float* W_ih1 = (const float*)d_in[5];
    const float* W_hh1 = (const float*)d_in[6];
    const float* b_ih1 = (const float*)d_in[7];
    const float* b_hh1 = (const float*)d_in[8];

    float* out = (float*)d_out;

    fused_rnn<<<BATCH, 512, 0, stream>>>(x, W_ih0, W_hh0, b_ih0, b_hh0,
                                         W_ih1, W_hh1, b_ih1, b_hh1, out);
}